// Round 11
// baseline (233.059 us; speedup 1.0000x reference)
//
#include <hip/hip_runtime.h>
#include <math.h>

// Problem constants
#define T_TOKENS 16384
#define HID      2048
#define NE       64
#define TOPK     8
// Tiling
#define TM       32              // tokens per block -> grid 512 = 2 blocks/CU
#define BK       128             // k-chunk
#define NCH      (HID / BK)      // 16
// A LDS geometry: row = 128 bf16 + 8 pad = 272 B; 68 dw == 4 mod 32 ->
// 32-row b128 frag reads: quarter-wave rows r,r+8 alias (2-way = free, m136).
#define RSTR     272
#define A_SPL    (TM * RSTR)     // 8704  : one A split plane
#define ABUF     (3 * A_SPL)     // 26112 : one buffer (3 planes)
#define LDS_BYTES (2 * ABUF)     // 52224 : double-buffered -> 2 blocks/CU

// Workspace layout:
//   [0, 786432)            : B planes, 32x32-frag layout (short8 units)
//   [786432, +8MB)         : f64 logits [T_TOKENS][NE]  (split mode only)
#define WS_LG_OFF   786432
#define WS_NEEDED   (WS_LG_OFF + (size_t)T_TOKENS * NE * 8)

typedef float    f32x4  __attribute__((ext_vector_type(4)));
typedef float    f32x16 __attribute__((ext_vector_type(16)));
typedef short    short8 __attribute__((ext_vector_type(8)));
typedef unsigned uint4v __attribute__((ext_vector_type(4)));

#define MFMA32(A, B, C) __builtin_amdgcn_mfma_f32_32x32x16_bf16((A), (B), (C), 0, 0, 0)

// RNE f2bf (probe only)
static __device__ __forceinline__ unsigned short f2bf(float x) {
    unsigned u = __builtin_bit_cast(unsigned, x);
    return (unsigned short)((u + 0x7FFFu + ((u >> 16) & 1u)) >> 16);
}

// 3-plane bf16 split of 8 floats, packed as 3 x uint4 (bit-identical to R4-R10).
static __device__ __forceinline__ void split8(const float4 v0, const float4 v1,
                                              uint4v& p0, uint4v& p1, uint4v& p2)
{
    const float x[8] = {v0.x, v0.y, v0.z, v0.w, v1.x, v1.y, v1.z, v1.w};
    #pragma unroll
    for (int j = 0; j < 4; ++j) {
        const float xe = x[2 * j], xo = x[2 * j + 1];
        const unsigned ue  = __builtin_bit_cast(unsigned, xe);
        const unsigned m0e = (ue + 0x8000u) & 0xFFFF0000u;
        const float    r1e = xe - __builtin_bit_cast(float, m0e);
        const unsigned u1e = __builtin_bit_cast(unsigned, r1e);
        const unsigned m1e = (u1e + 0x8000u) & 0xFFFF0000u;
        const float    r2e = r1e - __builtin_bit_cast(float, m1e);
        const unsigned u2e = __builtin_bit_cast(unsigned, r2e);
        const unsigned uo  = __builtin_bit_cast(unsigned, xo);
        const unsigned m0o = (uo + 0x8000u) & 0xFFFF0000u;
        const float    r1o = xo - __builtin_bit_cast(float, m0o);
        const unsigned u1o = __builtin_bit_cast(unsigned, r1o);
        const unsigned m1o = (u1o + 0x8000u) & 0xFFFF0000u;
        const float    r2o = r1o - __builtin_bit_cast(float, m1o);
        const unsigned u2o = __builtin_bit_cast(unsigned, r2o);
        p0[j] = m0o | (m0e >> 16);
        p1[j] = m1o | (m1e >> 16);
        p2[j] = (u2o & 0xFFFF0000u) | (u2e >> 16);
    }
}

// ---- pre-pass: split weight into 3 bf16 planes in 32x32 B-frag layout ----
// GEMM lane l of expert-half eh at k-step T reads short8 at
//   idx = plane*16384 + T*128 + eh*64 + l
// holding W[eh*32 + (l&31)][T*16 + (l>>5)*8 .. +7].
__global__ __launch_bounds__(256) void split_weight_kernel(
    const float* __restrict__ weight, uint4v* __restrict__ ws)
{
    const int n = blockIdx.x;      // expert 0..63
    const int o = threadIdx.x;     // k-octet 0..255 (k = 8*o)
    const float4 w0 = *(const float4*)&weight[(size_t)n * HID + o * 8];
    const float4 w1 = *(const float4*)&weight[(size_t)n * HID + o * 8 + 4];
    uint4v p0, p1, p2;
    split8(w0, w1, p0, p1, p2);
    const int t   = o >> 1;                    // k-step of 16
    const int idx = t * 128 + (n >> 5) * 64 + (o & 1) * 32 + (n & 31);
    ws[idx]         = p0;
    ws[idx + 16384] = p1;
    ws[idx + 32768] = p2;
}

// ---- main GEMM. Wave w: expert-half eh=w&1 (32 experts), K-half kh=w>>1.
//      Per step: 3 A ds_reads + 3 B loads -> 6 x mfma 32x32x16.
//      Cross-wave (kh) f64 reduction at the end via padded LDS exchange.
template<bool FUSED>
__global__ __launch_bounds__(256, 2) void router_kernel(
    const float* __restrict__ hidden,   // [T_TOKENS, HID] f32
    const short8* __restrict__ bfrag,   // pre-split B planes (frag layout)
    double* __restrict__ lgws,          // [T_TOKENS, NE] f64 (split mode)
    float* __restrict__ out_logits,     // [T_TOKENS, NE]
    float* __restrict__ out_vals,       // [T_TOKENS, TOPK]
    float* __restrict__ out_idxf)       // [T_TOKENS, TOPK]
{
    __shared__ __align__(16) char smem[LDS_BYTES];

    const int tid  = threadIdx.x;
    const int tok0 = blockIdx.x * TM;
    const int lane = tid & 63;
    const int wave = tid >> 6;
    const int eh   = wave & 1;   // expert half
    const int kh   = wave >> 1;  // K half of each chunk

    // A staging map (R6-verified): 32 rows x 8 threads x 16 consecutive f32
    const int ar   = tid >> 3;
    const int ac16 = (tid & 7) * 16;
    const float* aG = hidden + (size_t)(tok0 + ar) * HID + ac16;
    const int aWOff = ar * RSTR + ac16 * 2;      // bytes within a buffer

    // Frag bases. A: row = lane&31, in-row byte = (kh*64 + st*16 + (lane>>5)*8)*2
    const int aOff = (lane & 31) * RSTR + (lane >> 5) * 16 + kh * 128;
    const short8* bP = bfrag + eh * 64 + lane;

    f32x16 acch, accl;
    double accd[16];
    #pragma unroll
    for (int i = 0; i < 16; ++i) { acch[i] = 0.f; accl[i] = 0.f; accd[i] = 0.0; }

    float4 pa[4];

#define STAGE_A(dstbase) do {                                                     \
    uint4v p0_, p1_, p2_;                                                         \
    char* aW_ = (dstbase) + aWOff;                                                \
    split8(pa[0], pa[1], p0_, p1_, p2_);                                          \
    *(uint4v*)(aW_            ) = p0_;                                            \
    *(uint4v*)(aW_ +   A_SPL  ) = p1_;                                            \
    *(uint4v*)(aW_ + 2*A_SPL  ) = p2_;                                            \
    split8(pa[2], pa[3], p0_, p1_, p2_);                                          \
    *(uint4v*)(aW_             + 16) = p0_;                                       \
    *(uint4v*)(aW_ +   A_SPL   + 16) = p1_;                                       \
    *(uint4v*)(aW_ + 2*A_SPL   + 16) = p2_;                                       \
} while (0)

    // ---- prologue: stage chunk 0 ----
    #pragma unroll
    for (int q = 0; q < 4; ++q) pa[q] = *(const float4*)(aG + 4 * q);
    STAGE_A(smem);
    __syncthreads();

    for (int c = 0; c < NCH; ++c) {
        const char* bufc = smem + (c & 1) * ABUF;

        // T14: issue next chunk's A global loads first (hide under MFMA)
        if (c + 1 < NCH) {
            const int off = (c + 1) * BK;
            #pragma unroll
            for (int q = 0; q < 4; ++q) pa[q] = *(const float4*)(aG + off + 4 * q);
        }

        // ---- 4 k-steps of 16 (this wave's K-half) ----
        #pragma unroll
        for (int st = 0; st < 4; ++st) {
            const char* ab = bufc + aOff + st * 32;
            const short8 A0 = *(const short8*)(ab);
            const short8 A1 = *(const short8*)(ab + A_SPL);
            const short8 A2 = *(const short8*)(ab + 2 * A_SPL);
            const int T = (c * 8 + kh * 4 + st) * 128;
            const short8 B0 = bP[T];
            const short8 B1 = bP[T + 16384];
            const short8 B2 = bP[T + 32768];
            acch = MFMA32(A0, B0, acch);
            accl = MFMA32(A0, B1, accl);
            accl = MFMA32(A1, B0, accl);
            accl = MFMA32(A1, B1, accl);
            accl = MFMA32(A0, B2, accl);
            accl = MFMA32(A2, B0, accl);
        }

        // ---- span dump: hi-term f32 acc -> f64, reset ----
        #pragma unroll
        for (int i = 0; i < 16; ++i) accd[i] += (double)acch[i];
        #pragma unroll
        for (int i = 0; i < 16; ++i) acch[i] = 0.f;

        // ---- stage next chunk into the other buffer, ONE barrier ----
        if (c + 1 < NCH) {
            STAGE_A(smem + ((c & 1) ^ 1) * ABUF);
        }
        __syncthreads();
    }

    // ---- runtime D-layout probe for 32x32 (post-loop; self-correcting) ----
    int rowmap[16], colmap[16];
    {
        const unsigned short mb = f2bf((float)(lane & 31));  // exact in bf16
        const unsigned short ob = f2bf(0.0625f);             // 1/16 exact
        short8 vm, vo;
        #pragma unroll
        for (int j = 0; j < 8; ++j) { vm[j] = (short)mb; vo[j] = (short)ob; }
        f32x16 z;
        #pragma unroll
        for (int i = 0; i < 16; ++i) z[i] = 0.f;
        const f32x16 pr = MFMA32(vm, vo, z);  // slot value == row label
        const f32x16 pc = MFMA32(vo, vm, z);  // slot value == col label
        #pragma unroll
        for (int i = 0; i < 16; ++i) {
            rowmap[i] = (int)(pr[i] + 0.5f);
            colmap[i] = (int)(pc[i] + 0.5f);
        }
    }

    double lfin[16];
    #pragma unroll
    for (int i = 0; i < 16; ++i) lfin[i] = accd[i] + (double)accl[i];

    // ---- cross-wave K-half reduction (padded stride 17 f64: 4-way max) ----
    double* red = (double*)smem;   // [2][64][17] f64 = 17408 B (staging done)
    if (kh == 1) {
        #pragma unroll
        for (int i = 0; i < 16; ++i) red[(eh * 64 + lane) * 17 + i] = lfin[i];
    }
    __syncthreads();

    double (*lg)[NE + 1] = reinterpret_cast<double(*)[NE + 1]>(smem + 17408);

    if (kh == 0) {
        #pragma unroll
        for (int i = 0; i < 16; ++i) {
            lfin[i] += red[(eh * 64 + lane) * 17 + i];
            const int trow = rowmap[i];
            const int tok  = tok0 + trow;
            const int col  = eh * 32 + colmap[i];
            out_logits[(size_t)tok * NE + col] = (float)lfin[i];
            if constexpr (!FUSED) lgws[(size_t)tok * NE + col] = lfin[i];
            else                  lg[trow][col] = lfin[i];
        }
    }

    if constexpr (FUSED) {
        __syncthreads();
        // R6-verified in-block top-8
        for (int tt = wave; tt < TM; tt += 4) {
            double cur = lg[tt][lane];
            double first = 0.0;
            float  s = 0.f, myv = 0.f;
            int myi = 0;
            #pragma unroll
            for (int i = 0; i < TOPK; ++i) {
                double mv = cur;
                #pragma unroll
                for (int off = 32; off; off >>= 1) {
                    const double ov = __shfl_xor(mv, off);
                    mv = ov > mv ? ov : mv;
                }
                const unsigned long long m = __ballot(cur == mv);
                const int mi = __ffsll(m) - 1;
                if (i == 0) first = mv;
                const float e = expf((float)(mv - first));
                s += e;
                if (lane == i)  { myv = e; myi = mi; }
                if (lane == mi) cur = -INFINITY;
            }
            if (lane < TOPK) {
                const int tok = tok0 + tt;
                out_vals[(size_t)tok * TOPK + lane] = myv / s;
                out_idxf[(size_t)tok * TOPK + lane] = (float)myi;
            }
        }
    }
}

// ---- top-8 kernel (split mode): 1 token per wave, f64 logits from ws.
//      Same reduce/tie-break/softmax semantics as R3-R10.
__global__ __launch_bounds__(256) void topk_kernel(
    const double* __restrict__ lgws,
    float* __restrict__ out_vals,
    float* __restrict__ out_idxf)
{
    const int lane = threadIdx.x & 63;
    const int gw   = (blockIdx.x * 256 + threadIdx.x) >> 6;  // 0..4095
    for (int tok = gw; tok < T_TOKENS; tok += 4096) {
        double cur = lgws[(size_t)tok * NE + lane];
        double first = 0.0;
        float  s = 0.f, myv = 0.f;
        int myi = 0;
        #pragma unroll
        for (int i = 0; i < TOPK; ++i) {
            double mv = cur;
            #pragma unroll
            for (int off = 32; off; off >>= 1) {
                const double ov = __shfl_xor(mv, off);
                mv = ov > mv ? ov : mv;
            }
            const unsigned long long m = __ballot(cur == mv);
            const int mi = __ffsll(m) - 1;
            if (i == 0) first = mv;
            const float e = expf((float)(mv - first));
            s += e;
            if (lane == i)  { myv = e; myi = mi; }
            if (lane == mi) cur = -INFINITY;
        }
        if (lane < TOPK) {
            out_vals[(size_t)tok * TOPK + lane] = myv / s;
            out_idxf[(size_t)tok * TOPK + lane] = (float)myi;
        }
    }
}

extern "C" void kernel_launch(void* const* d_in, const int* in_sizes, int n_in,
                              void* d_out, int out_size, void* d_ws, size_t ws_size,
                              hipStream_t stream) {
    const float* hidden = (const float*)d_in[0];   // [16384, 2048] f32
    const float* weight = (const float*)d_in[1];   // [64, 2048] f32

    float* out        = (float*)d_out;
    float* out_logits = out;
    float* out_vals   = out + (size_t)T_TOKENS * NE;
    float* out_idxf   = out + (size_t)T_TOKENS * NE + (size_t)T_TOKENS * TOPK;

    uint4v* ws   = (uint4v*)d_ws;
    double* lgws = (double*)((char*)d_ws + WS_LG_OFF);

    hipLaunchKernelGGL(split_weight_kernel, dim3(NE), dim3(256), 0, stream,
                       weight, ws);

    if (ws_size >= WS_NEEDED) {
        hipLaunchKernelGGL((router_kernel<false>), dim3(T_TOKENS / TM), dim3(256),
                           0, stream, hidden, (const short8*)ws, lgws,
                           out_logits, out_vals, out_idxf);
        hipLaunchKernelGGL(topk_kernel, dim3(1024), dim3(256), 0, stream,
                           lgws, out_vals, out_idxf);
    } else {
        hipLaunchKernelGGL((router_kernel<true>), dim3(T_TOKENS / TM), dim3(256),
                           0, stream, hidden, (const short8*)ws, (double*)nullptr,
                           out_logits, out_vals, out_idxf);
    }
}

// Round 12
// 231.809 us; speedup vs baseline: 1.0054x; 1.0054x over previous
//
#include <hip/hip_runtime.h>
#include <math.h>

// Problem constants
#define T_TOKENS 16384
#define HID      2048
#define NE       64
#define TOPK     8
// Tiling: block = 256 thr = 4 waves; wave kh owns K-quarter (512 k) of a
// 32-token x 64-expert tile. NO LDS staging, NO k-loop barriers: each lane
// loads its own A-frag data straight from global (L1-resident lines) and
// splits in-register. Cross-wave f64 reduction once at the end.
#define TM       32              // tokens per block -> grid 512 = 2 blocks/CU
#define NSTEP    32              // k-steps of 16 per wave (K = 512)

// Workspace layout:
//   [0, 786432)  : B planes, 32x32-frag layout (short8 units)  [R11-verified]
//   [786432, +8MB): f64 logits [T_TOKENS][NE]  (split mode only)
#define WS_LG_OFF   786432
#define WS_NEEDED   (WS_LG_OFF + (size_t)T_TOKENS * NE * 8)

// LDS: reduction buffer only: [3][64][33] f64 = 50688 B -> 2 blocks/CU.
#define LDS_BYTES   50688

typedef float    f32x16 __attribute__((ext_vector_type(16)));
typedef short    short8 __attribute__((ext_vector_type(8)));
typedef unsigned uint4v __attribute__((ext_vector_type(4)));

#define MFMA32(A, B, C) __builtin_amdgcn_mfma_f32_32x32x16_bf16((A), (B), (C), 0, 0, 0)

// RNE f2bf (probe only)
static __device__ __forceinline__ unsigned short f2bf(float x) {
    unsigned u = __builtin_bit_cast(unsigned, x);
    return (unsigned short)((u + 0x7FFFu + ((u >> 16) & 1u)) >> 16);
}

// 3-plane bf16 split of 8 floats, packed as 3 x uint4 (bit-identical R4-R11).
static __device__ __forceinline__ void split8(const float4 v0, const float4 v1,
                                              uint4v& p0, uint4v& p1, uint4v& p2)
{
    const float x[8] = {v0.x, v0.y, v0.z, v0.w, v1.x, v1.y, v1.z, v1.w};
    #pragma unroll
    for (int j = 0; j < 4; ++j) {
        const float xe = x[2 * j], xo = x[2 * j + 1];
        const unsigned ue  = __builtin_bit_cast(unsigned, xe);
        const unsigned m0e = (ue + 0x8000u) & 0xFFFF0000u;
        const float    r1e = xe - __builtin_bit_cast(float, m0e);
        const unsigned u1e = __builtin_bit_cast(unsigned, r1e);
        const unsigned m1e = (u1e + 0x8000u) & 0xFFFF0000u;
        const float    r2e = r1e - __builtin_bit_cast(float, m1e);
        const unsigned u2e = __builtin_bit_cast(unsigned, r2e);
        const unsigned uo  = __builtin_bit_cast(unsigned, xo);
        const unsigned m0o = (uo + 0x8000u) & 0xFFFF0000u;
        const float    r1o = xo - __builtin_bit_cast(float, m0o);
        const unsigned u1o = __builtin_bit_cast(unsigned, r1o);
        const unsigned m1o = (u1o + 0x8000u) & 0xFFFF0000u;
        const float    r2o = r1o - __builtin_bit_cast(float, m1o);
        const unsigned u2o = __builtin_bit_cast(unsigned, r2o);
        p0[j] = m0o | (m0e >> 16);
        p1[j] = m1o | (m1e >> 16);
        p2[j] = (u2o & 0xFFFF0000u) | (u2e >> 16);
    }
}

// ---- pre-pass: split weight into 3 bf16 planes, 32x32 B-frag layout ----
// (R11-verified.) GEMM lane l of expert-half eh at k-step T=k/16 reads
//   idx = plane*16384 + T*128 + eh*64 + l
// holding W[eh*32 + (l&31)][T*16 + (l>>5)*8 .. +7].
__global__ __launch_bounds__(256) void split_weight_kernel(
    const float* __restrict__ weight, uint4v* __restrict__ ws)
{
    const int n = blockIdx.x;      // expert 0..63
    const int o = threadIdx.x;     // k-octet 0..255 (k = 8*o)
    const float4 w0 = *(const float4*)&weight[(size_t)n * HID + o * 8];
    const float4 w1 = *(const float4*)&weight[(size_t)n * HID + o * 8 + 4];
    uint4v p0, p1, p2;
    split8(w0, w1, p0, p1, p2);
    const int t   = o >> 1;                    // k-step of 16
    const int idx = t * 128 + (n >> 5) * 64 + (o & 1) * 32 + (n & 31);
    ws[idx]         = p0;
    ws[idx + 16384] = p1;
    ws[idx + 32768] = p2;
}

template<bool FUSED>
__global__ __launch_bounds__(256, 2) void router_kernel(
    const float* __restrict__ hidden,   // [T_TOKENS, HID] f32
    const short8* __restrict__ bfrag,   // pre-split B planes (frag layout)
    double* __restrict__ lgws,          // [T_TOKENS, NE] f64 (split mode)
    float* __restrict__ out_logits,     // [T_TOKENS, NE]
    float* __restrict__ out_vals,       // [T_TOKENS, TOPK]
    float* __restrict__ out_idxf)       // [T_TOKENS, TOPK]
{
    __shared__ __align__(16) char smem[LDS_BYTES];
    double* red = (double*)smem;        // [3][64][33] f64, slot-wise exchange

    const int tid  = threadIdx.x;
    const int tok0 = blockIdx.x * TM;
    const int lane = tid & 63;
    const int kh   = tid >> 6;          // K-quarter of this wave

    // A: lane owns row (lane&31), k-octet (lane>>5) of every 16-k step.
    const int arow = lane & 31;
    const float* aRow = hidden + (size_t)(tok0 + arow) * HID + (lane >> 5) * 8;

    // B frag pointers for the two expert halves
    const short8* bP0 = bfrag + lane;        // experts 0..31
    const short8* bP1 = bfrag + 64 + lane;   // experts 32..63

    f32x16 acch0, acch1, accl0, accl1;
    #pragma unroll
    for (int i = 0; i < 16; ++i) {
        acch0[i] = 0.f; acch1[i] = 0.f; accl0[i] = 0.f; accl1[i] = 0.f;
    }

    // ---- k-loop: no LDS, no barriers. 32 steps of K=16. ----
    #pragma unroll 4
    for (int s = 0; s < NSTEP; ++s) {
        const int k = (s >> 1) * 128 + kh * 32 + (s & 1) * 16;
        const float4 a0 = *(const float4*)(aRow + k);
        const float4 a1 = *(const float4*)(aRow + k + 4);
        uint4v p0, p1, p2;
        split8(a0, a1, p0, p1, p2);
        const short8 A0 = __builtin_bit_cast(short8, p0);
        const short8 A1 = __builtin_bit_cast(short8, p1);
        const short8 A2 = __builtin_bit_cast(short8, p2);
        const int T = (k >> 4) * 128;
        const short8 B00 = bP0[T];
        const short8 B01 = bP0[T + 16384];
        const short8 B02 = bP0[T + 32768];
        const short8 B10 = bP1[T];
        const short8 B11 = bP1[T + 16384];
        const short8 B12 = bP1[T + 32768];
        // 12 MFMAs; the two eh accl chains interleave (dep distance 2)
        acch0 = MFMA32(A0, B00, acch0);
        acch1 = MFMA32(A0, B10, acch1);
        accl0 = MFMA32(A1, B00, accl0);
        accl1 = MFMA32(A1, B10, accl1);
        accl0 = MFMA32(A0, B01, accl0);
        accl1 = MFMA32(A0, B11, accl1);
        accl0 = MFMA32(A1, B01, accl0);
        accl1 = MFMA32(A1, B11, accl1);
        accl0 = MFMA32(A0, B02, accl0);
        accl1 = MFMA32(A0, B12, accl1);
        accl0 = MFMA32(A2, B00, accl0);
        accl1 = MFMA32(A2, B10, accl1);
    }

    // ---- per-wave f64 partials (f32 accum depth is only 32 -> err ~1e-7) ----
    double lf0[16], lf1[16];
    #pragma unroll
    for (int i = 0; i < 16; ++i) {
        lf0[i] = (double)acch0[i] + (double)accl0[i];
        lf1[i] = (double)acch1[i] + (double)accl1[i];
    }

    // ---- cross-wave K-quarter reduction, slot-wise (lane mapping is
    //      identical across waves, so no layout probe needed to reduce) ----
    if (kh != 0) {
        double* r = red + ((kh - 1) * 64 + lane) * 33;
        #pragma unroll
        for (int i = 0; i < 16; ++i) { r[i] = lf0[i]; r[16 + i] = lf1[i]; }
    }
    __syncthreads();

    if (kh == 0) {
        #pragma unroll
        for (int q = 0; q < 3; ++q) {
            const double* r = red + (q * 64 + lane) * 33;
            #pragma unroll
            for (int i = 0; i < 16; ++i) { lf0[i] += r[i]; lf1[i] += r[16 + i]; }
        }

        // ---- runtime D-layout probe (R11-verified, self-correcting) ----
        int rowmap[16], colmap[16];
        {
            const unsigned short mb = f2bf((float)(lane & 31));
            const unsigned short ob = f2bf(0.0625f);
            short8 vm, vo;
            #pragma unroll
            for (int j = 0; j < 8; ++j) { vm[j] = (short)mb; vo[j] = (short)ob; }
            f32x16 z;
            #pragma unroll
            for (int i = 0; i < 16; ++i) z[i] = 0.f;
            const f32x16 pr = MFMA32(vm, vo, z);
            const f32x16 pc = MFMA32(vo, vm, z);
            #pragma unroll
            for (int i = 0; i < 16; ++i) {
                rowmap[i] = (int)(pr[i] + 0.5f);
                colmap[i] = (int)(pc[i] + 0.5f);
            }
        }

        double (*lg)[65] = reinterpret_cast<double(*)[65]>(smem);
        #pragma unroll
        for (int i = 0; i < 16; ++i) {
            const int trow = rowmap[i];
            const int tok  = tok0 + trow;
            const int c0   = colmap[i];
            out_logits[(size_t)tok * NE + c0]      = (float)lf0[i];
            out_logits[(size_t)tok * NE + c0 + 32] = (float)lf1[i];
            if constexpr (!FUSED) {
                lgws[(size_t)tok * NE + c0]      = lf0[i];
                lgws[(size_t)tok * NE + c0 + 32] = lf1[i];
            } else {
                lg[trow][c0]      = lf0[i];
                lg[trow][c0 + 32] = lf1[i];
            }
        }
    }

    if constexpr (FUSED) {
        __syncthreads();
        double (*lg)[65] = reinterpret_cast<double(*)[65]>(smem);
        // R6-verified in-block top-8
        for (int tt = kh; tt < TM; tt += 4) {
            double cur = lg[tt][lane];
            double first = 0.0;
            float  s = 0.f, myv = 0.f;
            int myi = 0;
            #pragma unroll
            for (int i = 0; i < TOPK; ++i) {
                double mv = cur;
                #pragma unroll
                for (int off = 32; off; off >>= 1) {
                    const double ov = __shfl_xor(mv, off);
                    mv = ov > mv ? ov : mv;
                }
                const unsigned long long m = __ballot(cur == mv);
                const int mi = __ffsll(m) - 1;
                if (i == 0) first = mv;
                const float e = expf((float)(mv - first));
                s += e;
                if (lane == i)  { myv = e; myi = mi; }
                if (lane == mi) cur = -INFINITY;
            }
            if (lane < TOPK) {
                const int tok = tok0 + tt;
                out_vals[(size_t)tok * TOPK + lane] = myv / s;
                out_idxf[(size_t)tok * TOPK + lane] = (float)myi;
            }
        }
    }
}

// ---- top-8 kernel (split mode): 1 token per wave, f64 logits from ws.
//      Same reduce/tie-break/softmax semantics as R3-R11.
__global__ __launch_bounds__(256) void topk_kernel(
    const double* __restrict__ lgws,
    float* __restrict__ out_vals,
    float* __restrict__ out_idxf)
{
    const int lane = threadIdx.x & 63;
    const int gw   = (blockIdx.x * 256 + threadIdx.x) >> 6;  // 0..4095
    for (int tok = gw; tok < T_TOKENS; tok += 4096) {
        double cur = lgws[(size_t)tok * NE + lane];
        double first = 0.0;
        float  s = 0.f, myv = 0.f;
        int myi = 0;
        #pragma unroll
        for (int i = 0; i < TOPK; ++i) {
            double mv = cur;
            #pragma unroll
            for (int off = 32; off; off >>= 1) {
                const double ov = __shfl_xor(mv, off);
                mv = ov > mv ? ov : mv;
            }
            const unsigned long long m = __ballot(cur == mv);
            const int mi = __ffsll(m) - 1;
            if (i == 0) first = mv;
            const float e = expf((float)(mv - first));
            s += e;
            if (lane == i)  { myv = e; myi = mi; }
            if (lane == mi) cur = -INFINITY;
        }
        if (lane < TOPK) {
            out_vals[(size_t)tok * TOPK + lane] = myv / s;
            out_idxf[(size_t)tok * TOPK + lane] = (float)myi;
        }
    }
}

extern "C" void kernel_launch(void* const* d_in, const int* in_sizes, int n_in,
                              void* d_out, int out_size, void* d_ws, size_t ws_size,
                              hipStream_t stream) {
    const float* hidden = (const float*)d_in[0];   // [16384, 2048] f32
    const float* weight = (const float*)d_in[1];   // [64, 2048] f32

    float* out        = (float*)d_out;
    float* out_logits = out;
    float* out_vals   = out + (size_t)T_TOKENS * NE;
    float* out_idxf   = out + (size_t)T_TOKENS * NE + (size_t)T_TOKENS * TOPK;

    uint4v* ws   = (uint4v*)d_ws;
    double* lgws = (double*)((char*)d_ws + WS_LG_OFF);

    hipLaunchKernelGGL(split_weight_kernel, dim3(NE), dim3(256), 0, stream,
                       weight, ws);

    if (ws_size >= WS_NEEDED) {
        hipLaunchKernelGGL((router_kernel<false>), dim3(T_TOKENS / TM), dim3(256),
                           0, stream, hidden, (const short8*)ws, lgws,
                           out_logits, out_vals, out_idxf);
        hipLaunchKernelGGL(topk_kernel, dim3(1024), dim3(256), 0, stream,
                           lgws, out_vals, out_idxf);
    } else {
        hipLaunchKernelGGL((router_kernel<true>), dim3(T_TOKENS / TM), dim3(256),
                           0, stream, hidden, (const short8*)ws, (double*)nullptr,
                           out_logits, out_vals, out_idxf);
    }
}